// Round 8
// baseline (622.276 us; speedup 1.0000x reference)
//
#include <hip/hip_runtime.h>

// Problem constants (from reference)
constexpr int N   = 50000;
constexpr int E   = 800000;
constexpr int FIN = 512;
constexpr int H1v = 256;
constexpr int H2v = 32;
constexpr int Cv  = 16;

constexpr int NBLK = (N + 1023) / 1024;  // 49 scan blocks

typedef __attribute__((ext_vector_type(8))) short short8;            // 8 bf16 (MFMA frag)
typedef __attribute__((ext_vector_type(4))) float f32x4;             // MFMA C/D frag
typedef __attribute__((ext_vector_type(4))) unsigned short us4;      // 4 bf16
typedef __attribute__((ext_vector_type(4))) unsigned int uint4v;

// fp32 -> bf16 round-to-nearest-even, and back
__device__ inline unsigned short f2bf(float f) {
    unsigned u = __float_as_uint(f);
    return (unsigned short)((u + 0x7FFFu + ((u >> 16) & 1u)) >> 16);
}
__device__ inline float bf2f(unsigned short b) { return __uint_as_float(((unsigned)b) << 16); }

// ---------------- degree histogram / CSR build ----------------

__global__ __launch_bounds__(256) void k_hist(const int* __restrict__ dst,
                                              int* __restrict__ cnt) {
    int e = blockIdx.x * 256 + threadIdx.x;
    if (e < E) atomicAdd(&cnt[dst[e]], 1);
}

// Phase 1: per-block (1024 elems) sums.
__global__ __launch_bounds__(256) void k_scan_part(const int* __restrict__ cnt,
                                                   int* __restrict__ bsum) {
    __shared__ int red[256];
    const int t = threadIdx.x;
    const int base = blockIdx.x * 1024 + t * 4;
    int s = 0;
#pragma unroll
    for (int i = 0; i < 4; ++i) {
        int idx = base + i;
        if (idx < N) s += cnt[idx];
    }
    red[t] = s;
    __syncthreads();
    for (int off = 128; off > 0; off >>= 1) {
        if (t < off) red[t] += red[t + off];
        __syncthreads();
    }
    if (t == 0) bsum[blockIdx.x] = red[0];
}

// Phase 2: one wave scans the 49 block sums.
__global__ __launch_bounds__(64) void k_scan_top(const int* __restrict__ bsum,
                                                 int* __restrict__ boff,
                                                 int* __restrict__ row_ptr) {
    const int l = threadIdx.x;
    int orig = (l < NBLK) ? bsum[l] : 0;
    int v = orig;
    for (int off = 1; off < 64; off <<= 1) {
        int u = __shfl_up(v, off, 64);
        if (l >= off) v += u;
    }
    if (l < NBLK) boff[l] = v - orig;          // exclusive block offset
    if (l == NBLK - 1) row_ptr[N] = v;          // total == E
}

// Phase 3: block-local scan + block offset -> row_ptr, cursor, dinv.
// In-place safe vs cnt: each block reads only its own disjoint 1024-range
// into registers before any write.
__global__ __launch_bounds__(256) void k_scan_final(const int* __restrict__ cnt,
                                                    const int* __restrict__ boff,
                                                    int* __restrict__ row_ptr,
                                                    int* __restrict__ cursor,
                                                    float* __restrict__ dinv) {
    __shared__ int sums[256];
    const int t = threadIdx.x;
    const int base = blockIdx.x * 1024 + t * 4;
    int v[4];
    int local = 0;
#pragma unroll
    for (int i = 0; i < 4; ++i) {
        int idx = base + i;
        v[i] = (idx < N) ? cnt[idx] : 0;
        local += v[i];
    }
    sums[t] = local;
    __syncthreads();
    for (int off = 1; off < 256; off <<= 1) {
        int u = (t >= off) ? sums[t - off] : 0;
        __syncthreads();
        sums[t] += u;
        __syncthreads();
    }
    int run = boff[blockIdx.x] + sums[t] - local;  // exclusive thread offset
#pragma unroll
    for (int i = 0; i < 4; ++i) {
        int idx = base + i;
        if (idx < N) {
            row_ptr[idx] = run;
            cursor[idx] = run;
            dinv[idx] = rsqrtf(1.0f + (float)v[i]);  // +1 self-loop
        }
        run += v[i];
    }
}

__global__ __launch_bounds__(256) void k_permute(const int* __restrict__ src,
                                                 const int* __restrict__ dst,
                                                 int* __restrict__ cursor,
                                                 int* __restrict__ srcs) {
    int e = blockIdx.x * 256 + threadIdx.x;
    if (e < E) {
        int pos = atomicAdd(&cursor[dst[e]], 1);
        srcs[pos] = src[e];
    }
}

// ---------------- W1 split: fp32 [512][256] -> bf16 hi/lo in MFMA B-frag layout ----
// Tile (ktg 0..15, ntg 0..15): B[k][n], k = ktg*32 + (l>>4)*8 + j, n = ntg*16 + (l&15).
// Storage (ushorts): tile base = ((ktg*16+ntg)*2)*512; hi at +l*8, lo at +512+l*8.

__global__ __launch_bounds__(256) void k_wsplit(const float* __restrict__ W,
                                                unsigned short* __restrict__ Wf) {
    int t = blockIdx.x * 256 + threadIdx.x;  // 0..16383
    int l = t & 63, nt = (t >> 6) & 15, kt = t >> 10;
    int n = nt * 16 + (l & 15);
    int kb = kt * 32 + (l >> 4) * 8;
    short8 h8, l8;
#pragma unroll
    for (int j = 0; j < 8; ++j) {
        float w = W[(size_t)(kb + j) * H1v + n];
        unsigned short h = f2bf(w);
        h8[j] = (short)h;
        l8[j] = (short)f2bf(w - bf2f(h));
    }
    size_t base = ((size_t)(kt * 16 + nt) * 2) * 512 + (size_t)l * 8;
    *(short8*)(Wf + base) = h8;
    *(short8*)(Wf + base + 512) = l8;
}

// ---------------- GEMM 1 (MFMA, split-bf16 x3, LDS-free, pipelined) -------------
// [N,512] @ [512,256], *dinv, bf16 out.  Grid (391,2), 4 waves at 64x64 quadrants.
// Latency structure (round-8 fix):
//   - A: distance-2 double-buffer (abuf[2]); HBM latency (~900 cyc) covered by
//     ~2 iterations of MFMA+VALU work.
//   - B: issued at top of iteration, consumed after the ~200-cyc A-split VALU
//     block (covers L2 latency).
//   - MFMA issued term-major: dependent ops on the same acc are 15 apart.

__device__ inline void split_pair(float x0, float x1, unsigned& hp, unsigned& lp) {
    unsigned u0 = __float_as_uint(x0), u1 = __float_as_uint(x1);
    unsigned h0 = u0 & 0xffff0000u, h1 = u1 & 0xffff0000u;
    float l0 = x0 - __uint_as_float(h0);
    float l1 = x1 - __uint_as_float(h1);
    hp = __builtin_amdgcn_perm(u1, u0, 0x07060302u);  // [u0.hi16, u1.hi16]
    lp = __builtin_amdgcn_perm(__float_as_uint(l1), __float_as_uint(l0), 0x07060302u);
}

__device__ inline void split_frag(const float4& a, const float4& b, short8& hi, short8& lo) {
    unsigned h0, h1, h2, h3, l0, l1, l2, l3;
    split_pair(a.x, a.y, h0, l0);
    split_pair(a.z, a.w, h1, l1);
    split_pair(b.x, b.y, h2, l2);
    split_pair(b.z, b.w, h3, l3);
    uint4v h, l;
    h[0] = h0; h[1] = h1; h[2] = h2; h[3] = h3;
    l[0] = l0; l[1] = l1; l[2] = l2; l[3] = l3;
    hi = __builtin_bit_cast(short8, h);
    lo = __builtin_bit_cast(short8, l);
}

__global__ __launch_bounds__(256, 2) void k_gemm1_mfma(const float* __restrict__ X,
                                                       const unsigned short* __restrict__ Wf,
                                                       const float* __restrict__ dinv,
                                                       unsigned short* __restrict__ Hout) {
    const int tid = threadIdx.x;
    const int w = tid >> 6, l = tid & 63;
    const int wr = w >> 1, wc = w & 1;
    const int row0 = blockIdx.x * 128 + wr * 64;
    const int colb = blockIdx.y;
    const int lm = l & 15;
    const int lk = (l >> 4) * 8;

    const float4 zero4 = make_float4(0.f, 0.f, 0.f, 0.f);

    // A frag row pointers (4 i-tiles)
    const float* ap[4];
    bool ok[4];
#pragma unroll
    for (int i = 0; i < 4; ++i) {
        int r = row0 + i * 16 + lm;
        ok[i] = r < N;
        ap[i] = X + (size_t)r * FIN + lk;
    }
    // B frag lane pointer (tiles ntg = colb*8 + wc*4 + j)
    const unsigned short* bp0 = Wf + (size_t)(colb * 8 + wc * 4) * 1024 + (size_t)l * 8;

    f32x4 acc[4][4];
#pragma unroll
    for (int i = 0; i < 4; ++i)
#pragma unroll
        for (int j = 0; j < 4; ++j) acc[i][j] = (f32x4)0.f;

    // A double-buffer: preload K-tiles 0 and 1
    float4 abuf[2][8];
#pragma unroll
    for (int s = 0; s < 2; ++s)
#pragma unroll
        for (int i = 0; i < 4; ++i) {
            abuf[s][2 * i]     = ok[i] ? *(const float4*)(ap[i] + s * 32)     : zero4;
            abuf[s][2 * i + 1] = ok[i] ? *(const float4*)(ap[i] + s * 32 + 4) : zero4;
        }

#pragma unroll
    for (int k = 0; k < 16; ++k) {
        const int par = k & 1;

        // ---- B for this K-tile: issue first (L2-hot, latency covered by split VALU)
        const unsigned short* bp = bp0 + (size_t)k * 16384;
        short8 Bh[4], Bl[4];
#pragma unroll
        for (int j = 0; j < 4; ++j) {
            Bh[j] = *(const short8*)(bp + j * 1024);
            Bl[j] = *(const short8*)(bp + j * 1024 + 512);
        }

        // ---- split current A (K-tile k) into hi/lo frags (~200 cyc VALU)
        short8 Ah[4], Al[4];
#pragma unroll
        for (int i = 0; i < 4; ++i)
            split_frag(abuf[par][2 * i], abuf[par][2 * i + 1], Ah[i], Al[i]);

        // ---- prefetch A for K-tile k+2 into the parity slot just consumed
        if (k < 14) {
#pragma unroll
            for (int i = 0; i < 4; ++i) {
                const float* pa = ap[i] + (k + 2) * 32;
                abuf[par][2 * i]     = ok[i] ? *(const float4*)(pa)     : zero4;
                abuf[par][2 * i + 1] = ok[i] ? *(const float4*)(pa + 4) : zero4;
            }
        }

        // ---- MFMA, term-major (independent accs back-to-back)
#pragma unroll
        for (int i = 0; i < 4; ++i)
#pragma unroll
            for (int j = 0; j < 4; ++j)
                acc[i][j] = __builtin_amdgcn_mfma_f32_16x16x32_bf16(Ah[i], Bh[j], acc[i][j], 0, 0, 0);
#pragma unroll
        for (int i = 0; i < 4; ++i)
#pragma unroll
            for (int j = 0; j < 4; ++j)
                acc[i][j] = __builtin_amdgcn_mfma_f32_16x16x32_bf16(Ah[i], Bl[j], acc[i][j], 0, 0, 0);
#pragma unroll
        for (int i = 0; i < 4; ++i)
#pragma unroll
            for (int j = 0; j < 4; ++j)
                acc[i][j] = __builtin_amdgcn_mfma_f32_16x16x32_bf16(Al[i], Bh[j], acc[i][j], 0, 0, 0);
    }

    // ---- epilogue: C row = (l>>4)*4 + reg, col = l&15 ; *dinv[row], store bf16 ----
    const int col0 = colb * 128;
#pragma unroll
    for (int i = 0; i < 4; ++i) {
        int rbase = row0 + i * 16 + (l >> 4) * 4;
        float dv[4];
        bool okr[4];
#pragma unroll
        for (int r = 0; r < 4; ++r) {
            int rr = rbase + r;
            okr[r] = rr < N;
            dv[r] = okr[r] ? dinv[rr] : 0.f;
        }
#pragma unroll
        for (int j = 0; j < 4; ++j) {
            int col = col0 + (wc * 4 + j) * 16 + lm;
#pragma unroll
            for (int r = 0; r < 4; ++r)
                if (okr[r]) Hout[(size_t)(rbase + r) * H1v + col] = f2bf(acc[i][j][r] * dv[r]);
        }
    }
}

// ---------------- GEMM 2: [N,256] @ [256,32] fp32 in, *dinv, bf16 out ----------------

__global__ __launch_bounds__(256) void k_gemm2(const float* __restrict__ A,
                                               const float* __restrict__ W,
                                               const float* __restrict__ dinv,
                                               unsigned short* __restrict__ Hout) {
    __shared__ float Ws[H1v * H2v];  // 32 KB
    const int tid = threadIdx.x;
#pragma unroll
    for (int i = 0; i < 8; ++i) {
        int off = tid * 4 + i * 1024;
        *(float4*)(&Ws[off]) = *(const float4*)(W + off);
    }
    __syncthreads();

    const int row = blockIdx.x * 8 + (tid >> 5);
    const int col = tid & 31;
    if (row >= N) return;
    const float* arow = A + (size_t)row * H1v;
    float sum = 0.f;
#pragma unroll 4
    for (int k = 0; k < H1v; k += 4) {
        float4 a4 = *(const float4*)(arow + k);
        sum = fmaf(a4.x, Ws[(k + 0) * H2v + col], sum);
        sum = fmaf(a4.y, Ws[(k + 1) * H2v + col], sum);
        sum = fmaf(a4.z, Ws[(k + 2) * H2v + col], sum);
        sum = fmaf(a4.w, Ws[(k + 3) * H2v + col], sum);
    }
    Hout[(size_t)row * H2v + col] = f2bf(sum * dinv[row]);
}

// ---------------- GEMM 3: [N,32] @ [32,16] fp32 in, *dinv, bf16 out ----------------

__global__ __launch_bounds__(256) void k_gemm3(const float* __restrict__ A,
                                               const float* __restrict__ W,
                                               const float* __restrict__ dinv,
                                               unsigned short* __restrict__ Hout) {
    __shared__ float Ws[H2v * Cv];
    const int tid = threadIdx.x;
    *(float2*)(&Ws[tid * 2]) = *(const float2*)(W + tid * 2);
    __syncthreads();

    const int row = blockIdx.x * 16 + (tid >> 4);
    const int col = tid & 15;
    if (row >= N) return;
    const float* arow = A + (size_t)row * H2v;
    float sum = 0.f;
#pragma unroll
    for (int k = 0; k < H2v; ++k) sum = fmaf(arow[k], Ws[k * Cv + col], sum);
    Hout[(size_t)row * Cv + col] = f2bf(sum * dinv[row]);
}

// ---------------- CSR aggregation (atomic-free, bf16 messages, fp32 accum) -------
// h holds bf16 h'[i] = dinv[i]*(a@W)[i].  out[d] = dinv[d]*(sum h'[s] + h'[d]) + b

__global__ __launch_bounds__(256) void k_agg_d256(const unsigned short* __restrict__ h,
                                                  const int* __restrict__ rp,
                                                  const int* __restrict__ srcs,
                                                  const float* __restrict__ dinv,
                                                  const float* __restrict__ bias,
                                                  float* __restrict__ out) {
    const int wave = threadIdx.x >> 6;
    const int lane = threadIdx.x & 63;
    const int d = blockIdx.x * 4 + wave;
    if (d >= N) return;
    const int beg = rp[d], end = rp[d + 1];
    const int fo = lane * 4;
    us4 sv = *(const us4*)(h + (size_t)d * H1v + fo);  // self-loop
    float ax = bf2f(sv.x), ay = bf2f(sv.y), az = bf2f(sv.z), aw = bf2f(sv.w);
    int j = beg;
    for (; j + 3 < end; j += 4) {  // 4 independent gathers in flight
        int s0 = srcs[j], s1 = srcs[j + 1], s2 = srcs[j + 2], s3 = srcs[j + 3];
        us4 v0 = *(const us4*)(h + (size_t)s0 * H1v + fo);
        us4 v1 = *(const us4*)(h + (size_t)s1 * H1v + fo);
        us4 v2 = *(const us4*)(h + (size_t)s2 * H1v + fo);
        us4 v3 = *(const us4*)(h + (size_t)s3 * H1v + fo);
        ax += bf2f(v0.x) + bf2f(v1.x) + bf2f(v2.x) + bf2f(v3.x);
        ay += bf2f(v0.y) + bf2f(v1.y) + bf2f(v2.y) + bf2f(v3.y);
        az += bf2f(v0.z) + bf2f(v1.z) + bf2f(v2.z) + bf2f(v3.z);
        aw += bf2f(v0.w) + bf2f(v1.w) + bf2f(v2.w) + bf2f(v3.w);
    }
    for (; j < end; ++j) {
        us4 v = *(const us4*)(h + (size_t)srcs[j] * H1v + fo);
        ax += bf2f(v.x); ay += bf2f(v.y); az += bf2f(v.z); aw += bf2f(v.w);
    }
    const float di = dinv[d];
    const float4 b4 = *(const float4*)(bias + fo);
    float4 o;
    o.x = fmaxf(fmaf(di, ax, b4.x), 0.f);
    o.y = fmaxf(fmaf(di, ay, b4.y), 0.f);
    o.z = fmaxf(fmaf(di, az, b4.z), 0.f);
    o.w = fmaxf(fmaf(di, aw, b4.w), 0.f);
    *(float4*)(out + (size_t)d * H1v + fo) = o;
}

template <int D, bool RELU>
__global__ __launch_bounds__(256) void k_agg_small(const unsigned short* __restrict__ h,
                                                   const int* __restrict__ rp,
                                                   const int* __restrict__ srcs,
                                                   const float* __restrict__ dinv,
                                                   const float* __restrict__ bias,
                                                   float* __restrict__ out) {
    constexpr int PER = 256 / D;
    const int sub = threadIdx.x / D;
    const int f = threadIdx.x % D;
    const int d = blockIdx.x * PER + sub;
    if (d >= N) return;
    const int beg = rp[d], end = rp[d + 1];
    float acc = bf2f(h[(size_t)d * D + f]);  // self-loop
    int j = beg;
    for (; j + 3 < end; j += 4) {
        float v0 = bf2f(h[(size_t)srcs[j] * D + f]);
        float v1 = bf2f(h[(size_t)srcs[j + 1] * D + f]);
        float v2 = bf2f(h[(size_t)srcs[j + 2] * D + f]);
        float v3 = bf2f(h[(size_t)srcs[j + 3] * D + f]);
        acc += v0 + v1 + v2 + v3;
    }
    for (; j < end; ++j) acc += bf2f(h[(size_t)srcs[j] * D + f]);
    float v = fmaf(dinv[d], acc, bias[f]);
    if (RELU) v = fmaxf(v, 0.f);
    out[(size_t)d * D + f] = v;
}

// ---------------- launch ----------------

extern "C" void kernel_launch(void* const* d_in, const int* in_sizes, int n_in,
                              void* d_out, int out_size, void* d_ws, size_t ws_size,
                              hipStream_t stream) {
    const float* x  = (const float*)d_in[0];
    const int*   ei = (const int*)d_in[1];
    const float* W1 = (const float*)d_in[2];
    const float* b1 = (const float*)d_in[3];
    const float* W2 = (const float*)d_in[4];
    const float* b2 = (const float*)d_in[5];
    const float* W3 = (const float*)d_in[6];
    const float* b3 = (const float*)d_in[7];
    const int* src = ei;       // edge_index[0]
    const int* dst = ei + E;   // edge_index[1]
    float* out = (float*)d_out;

    // Workspace layout (bytes):
    // [0       ] dinv    float[50000]
    // [0x40000 ] cnt/rp  int[50001]   (in-place scan)
    // [0x80000 ] cursor  int[50000]
    // [0xB2000 ] bsum    int[49]
    // [0xB3000 ] boff    int[49]
    // [0xC0000 ] srcs    int[800000]
    // [4 MiB   ] Wsplit  ushort[262144]  (512 KB)
    // [5 MiB   ] h1 bf16, a1 fp32, h2 bf16, a2 fp32, h3 bf16   total ~93 MB
    char* ws = (char*)d_ws;
    float* dinv   = (float*)ws;
    int*   cnt    = (int*)(ws + 0x40000);
    int*   rp     = cnt;
    int*   cursor = (int*)(ws + 0x80000);
    int*   bsum   = (int*)(ws + 0xB2000);
    int*   boff   = (int*)(ws + 0xB3000);
    int*   srcs   = (int*)(ws + 0xC0000);
    unsigned short* wsplit = (unsigned short*)(ws + (size_t)4 * 1024 * 1024);
    char* p = ws + (size_t)5 * 1024 * 1024;
    unsigned short* h1 = (unsigned short*)p; p += (size_t)N * H1v * sizeof(unsigned short);
    float*          a1 = (float*)p;          p += (size_t)N * H1v * sizeof(float);
    unsigned short* h2 = (unsigned short*)p; p += (size_t)N * H2v * sizeof(unsigned short);
    float*          a2 = (float*)p;          p += (size_t)N * H2v * sizeof(float);
    unsigned short* h3 = (unsigned short*)p;

    (void)hipMemsetAsync(cnt, 0, (N + 1) * sizeof(int), stream);
    k_hist<<<(E + 255) / 256, 256, 0, stream>>>(dst, cnt);
    k_scan_part<<<NBLK, 256, 0, stream>>>(cnt, bsum);
    k_scan_top<<<1, 64, 0, stream>>>(bsum, boff, rp);
    k_scan_final<<<NBLK, 256, 0, stream>>>(cnt, boff, rp, cursor, dinv);
    k_permute<<<(E + 255) / 256, 256, 0, stream>>>(src, dst, cursor, srcs);
    k_wsplit<<<64, 256, 0, stream>>>(W1, wsplit);

    // ---- layer 1: 512 -> 256 (MFMA, LDS-free, pipelined), ReLU ----
    dim3 g1((N + 127) / 128, 2);
    k_gemm1_mfma<<<g1, 256, 0, stream>>>(x, wsplit, dinv, h1);
    k_agg_d256<<<(N + 3) / 4, 256, 0, stream>>>(h1, rp, srcs, dinv, b1, a1);

    // ---- layer 2: 256 -> 32, ReLU ----
    k_gemm2<<<N / 8, 256, 0, stream>>>(a1, W2, dinv, h2);
    k_agg_small<32, true><<<N / 8, 256, 0, stream>>>(h2, rp, srcs, dinv, b2, a2);

    // ---- layer 3: 32 -> 16, no ReLU ----
    k_gemm3<<<N / 16, 256, 0, stream>>>(a2, W3, dinv, h3);
    k_agg_small<16, false><<<N / 16, 256, 0, stream>>>(h3, rp, srcs, dinv, b3, out);
}

// Round 9
// 465.892 us; speedup vs baseline: 1.3357x; 1.3357x over previous
//
#include <hip/hip_runtime.h>

// Problem constants (from reference)
constexpr int N   = 50000;
constexpr int E   = 800000;
constexpr int FIN = 512;
constexpr int H1v = 256;
constexpr int H2v = 32;
constexpr int Cv  = 16;

constexpr int NBLK = (N + 1023) / 1024;  // 49 scan blocks

typedef __attribute__((ext_vector_type(8))) short short8;            // 8 bf16 (MFMA frag)
typedef __attribute__((ext_vector_type(4))) float f32x4;             // MFMA C/D frag
typedef __attribute__((ext_vector_type(4))) unsigned short us4;      // 4 bf16
typedef __attribute__((ext_vector_type(4))) unsigned int uint4v;

// fp32 -> bf16 round-to-nearest-even, and back
__device__ inline unsigned short f2bf(float f) {
    unsigned u = __float_as_uint(f);
    return (unsigned short)((u + 0x7FFFu + ((u >> 16) & 1u)) >> 16);
}
__device__ inline float bf2f(unsigned short b) { return __uint_as_float(((unsigned)b) << 16); }

// ---------------- init: cnt zeroing + W1 split, fused (independent data) --------
// Blocks 0..63: W1 split into bf16 hi/lo MFMA B-frag layout.
// Blocks 64.. : cnt[0..N] = 0.
// W-frag layout: tile (ktg 0..15, ntg 0..15): B[k][n], k=ktg*32+(l>>4)*8+j,
// n=ntg*16+(l&15); tile base = ((ktg*16+ntg)*2)*512; hi at +l*8, lo at +512+l*8.

__global__ __launch_bounds__(256) void k_init(const float* __restrict__ W,
                                              unsigned short* __restrict__ Wf,
                                              int* __restrict__ cnt) {
    const int b = blockIdx.x;
    if (b < 64) {
        int t = b * 256 + threadIdx.x;  // 0..16383
        int l = t & 63, nt = (t >> 6) & 15, kt = t >> 10;
        int n = nt * 16 + (l & 15);
        int kb = kt * 32 + (l >> 4) * 8;
        short8 h8, l8;
#pragma unroll
        for (int j = 0; j < 8; ++j) {
            float w = W[(size_t)(kb + j) * H1v + n];
            unsigned short h = f2bf(w);
            h8[j] = (short)h;
            l8[j] = (short)f2bf(w - bf2f(h));
        }
        size_t base = ((size_t)(kt * 16 + nt) * 2) * 512 + (size_t)l * 8;
        *(short8*)(Wf + base) = h8;
        *(short8*)(Wf + base + 512) = l8;
    } else {
        int i = (b - 64) * 256 + threadIdx.x;
        if (i <= N) cnt[i] = 0;
    }
}

// ---------------- degree histogram / CSR build ----------------

__global__ __launch_bounds__(256) void k_hist(const int* __restrict__ dst,
                                              int* __restrict__ cnt) {
    int e = blockIdx.x * 256 + threadIdx.x;
    if (e < E) atomicAdd(&cnt[dst[e]], 1);
}

// Phase 1: per-block (1024 elems) sums.
__global__ __launch_bounds__(256) void k_scan_part(const int* __restrict__ cnt,
                                                   int* __restrict__ bsum) {
    __shared__ int red[256];
    const int t = threadIdx.x;
    const int base = blockIdx.x * 1024 + t * 4;
    int s = 0;
#pragma unroll
    for (int i = 0; i < 4; ++i) {
        int idx = base + i;
        if (idx < N) s += cnt[idx];
    }
    red[t] = s;
    __syncthreads();
    for (int off = 128; off > 0; off >>= 1) {
        if (t < off) red[t] += red[t + off];
        __syncthreads();
    }
    if (t == 0) bsum[blockIdx.x] = red[0];
}

// Phase 2 (fused top + final): block offset computed in-block from bsum (49 ints,
// one wave), then block-local scan -> row_ptr, cursor, dinv. In-place safe vs cnt:
// each block reads only its own disjoint 1024-range into registers before writes.
__global__ __launch_bounds__(256) void k_scan_final(const int* __restrict__ cnt,
                                                    const int* __restrict__ bsum,
                                                    int* __restrict__ row_ptr,
                                                    int* __restrict__ cursor,
                                                    float* __restrict__ dinv) {
    __shared__ int sums[256];
    __shared__ int s_bofs, s_tot;
    const int t = threadIdx.x;

    if (t < 64) {  // one wave: prefix-of-my-block + grand total over bsum[49]
        int v = (t < NBLK) ? bsum[t] : 0;
        int pre = (t < (int)blockIdx.x) ? v : 0;
#pragma unroll
        for (int off = 32; off > 0; off >>= 1) {
            pre += __shfl_down(pre, off, 64);
            v   += __shfl_down(v, off, 64);
        }
        if (t == 0) { s_bofs = pre; s_tot = v; }
    }

    const int base = blockIdx.x * 1024 + t * 4;
    int v[4];
    int local = 0;
#pragma unroll
    for (int i = 0; i < 4; ++i) {
        int idx = base + i;
        v[i] = (idx < N) ? cnt[idx] : 0;
        local += v[i];
    }
    sums[t] = local;
    __syncthreads();
    for (int off = 1; off < 256; off <<= 1) {
        int u = (t >= off) ? sums[t - off] : 0;
        __syncthreads();
        sums[t] += u;
        __syncthreads();
    }
    int run = s_bofs + sums[t] - local;  // exclusive thread offset
#pragma unroll
    for (int i = 0; i < 4; ++i) {
        int idx = base + i;
        if (idx < N) {
            row_ptr[idx] = run;
            cursor[idx] = run;
            dinv[idx] = rsqrtf(1.0f + (float)v[i]);  // +1 self-loop
        }
        run += v[i];
    }
    if (blockIdx.x == NBLK - 1 && t == 0) row_ptr[N] = s_tot;  // == E
}

__global__ __launch_bounds__(256) void k_permute(const int* __restrict__ src,
                                                 const int* __restrict__ dst,
                                                 int* __restrict__ cursor,
                                                 int* __restrict__ srcs) {
    int e = blockIdx.x * 256 + threadIdx.x;
    if (e < E) {
        int pos = atomicAdd(&cursor[dst[e]], 1);
        srcs[pos] = src[e];
    }
}

// ---------------- GEMM 1 (MFMA, split-bf16 x3, LDS-free): [N,512]@[512,256] ------
// ROUND-7 KNOWN-GOOD (110 us, 92 VGPR, no spill). Round-8's register double-buffer
// spilled to scratch (VGPR 128 + 5.6MB scratch writes) -> 2.4x regression. Keep
// distance-1 prefetch + interleaved MFMA; do NOT deepen the register pipeline.

__device__ inline void split_pair(float x0, float x1, unsigned& hp, unsigned& lp) {
    unsigned u0 = __float_as_uint(x0), u1 = __float_as_uint(x1);
    unsigned h0 = u0 & 0xffff0000u, h1 = u1 & 0xffff0000u;
    float l0 = x0 - __uint_as_float(h0);
    float l1 = x1 - __uint_as_float(h1);
    hp = __builtin_amdgcn_perm(u1, u0, 0x07060302u);  // [u0.hi16, u1.hi16]
    lp = __builtin_amdgcn_perm(__float_as_uint(l1), __float_as_uint(l0), 0x07060302u);
}

__device__ inline void split_frag(const float4& a, const float4& b, short8& hi, short8& lo) {
    unsigned h0, h1, h2, h3, l0, l1, l2, l3;
    split_pair(a.x, a.y, h0, l0);
    split_pair(a.z, a.w, h1, l1);
    split_pair(b.x, b.y, h2, l2);
    split_pair(b.z, b.w, h3, l3);
    uint4v h, l;
    h[0] = h0; h[1] = h1; h[2] = h2; h[3] = h3;
    l[0] = l0; l[1] = l1; l[2] = l2; l[3] = l3;
    hi = __builtin_bit_cast(short8, h);
    lo = __builtin_bit_cast(short8, l);
}

__global__ __launch_bounds__(256, 2) void k_gemm1_mfma(const float* __restrict__ X,
                                                       const unsigned short* __restrict__ Wf,
                                                       const float* __restrict__ dinv,
                                                       unsigned short* __restrict__ Hout) {
    const int tid = threadIdx.x;
    const int w = tid >> 6, l = tid & 63;
    const int wr = w >> 1, wc = w & 1;
    const int row0 = blockIdx.x * 128 + wr * 64;
    const int colb = blockIdx.y;
    const int lm = l & 15;
    const int lk = (l >> 4) * 8;

    // A frag row pointers (4 i-tiles)
    const float* ap[4];
    bool ok[4];
#pragma unroll
    for (int i = 0; i < 4; ++i) {
        int r = row0 + i * 16 + lm;
        ok[i] = r < N;
        ap[i] = X + (size_t)r * FIN + lk;
    }
    // B frag lane pointer (tiles ntg = colb*8 + wc*4 + j)
    const unsigned short* bp0 = Wf + (size_t)(colb * 8 + wc * 4) * 1024 + (size_t)l * 8;

    f32x4 acc[4][4];
#pragma unroll
    for (int i = 0; i < 4; ++i)
#pragma unroll
        for (int j = 0; j < 4; ++j) acc[i][j] = (f32x4)0.f;

    float4 a0[4], a1[4];
#pragma unroll
    for (int i = 0; i < 4; ++i) {
        a0[i] = ok[i] ? *(const float4*)(ap[i]) : make_float4(0.f, 0.f, 0.f, 0.f);
        a1[i] = ok[i] ? *(const float4*)(ap[i] + 4) : make_float4(0.f, 0.f, 0.f, 0.f);
    }

    for (int ktg = 0; ktg < 16; ++ktg) {
        // B frags for this K-tile (L2-hot, already frag layout)
        const unsigned short* bp = bp0 + (size_t)ktg * 16384;  // ktg*16 tiles * 1024
        short8 Bh[4], Bl[4];
#pragma unroll
        for (int j = 0; j < 4; ++j) {
            Bh[j] = *(const short8*)(bp + j * 1024);
            Bl[j] = *(const short8*)(bp + j * 1024 + 512);
        }

        // convert current A floats -> hi/lo frags
        short8 Ah[4], Al[4];
#pragma unroll
        for (int i = 0; i < 4; ++i) split_frag(a0[i], a1[i], Ah[i], Al[i]);

        // prefetch next K-tile's A
        if (ktg < 15) {
#pragma unroll
            for (int i = 0; i < 4; ++i) {
                const float* p = ap[i] + (ktg + 1) * 32;
                a0[i] = ok[i] ? *(const float4*)(p) : make_float4(0.f, 0.f, 0.f, 0.f);
                a1[i] = ok[i] ? *(const float4*)(p + 4) : make_float4(0.f, 0.f, 0.f, 0.f);
            }
        }

        // MFMA: 4x4 16x16 tiles, 3 split terms
#pragma unroll
        for (int i = 0; i < 4; ++i)
#pragma unroll
            for (int j = 0; j < 4; ++j) {
                acc[i][j] = __builtin_amdgcn_mfma_f32_16x16x32_bf16(Ah[i], Bh[j], acc[i][j], 0, 0, 0);
                acc[i][j] = __builtin_amdgcn_mfma_f32_16x16x32_bf16(Ah[i], Bl[j], acc[i][j], 0, 0, 0);
                acc[i][j] = __builtin_amdgcn_mfma_f32_16x16x32_bf16(Al[i], Bh[j], acc[i][j], 0, 0, 0);
            }
    }

    // ---- epilogue: C row = (l>>4)*4 + reg, col = l&15 ; *dinv[row], store bf16 ----
    const int col0 = colb * 128;
#pragma unroll
    for (int i = 0; i < 4; ++i) {
        int rbase = row0 + i * 16 + (l >> 4) * 4;
        float dv[4];
        bool okr[4];
#pragma unroll
        for (int r = 0; r < 4; ++r) {
            int rr = rbase + r;
            okr[r] = rr < N;
            dv[r] = okr[r] ? dinv[rr] : 0.f;
        }
#pragma unroll
        for (int j = 0; j < 4; ++j) {
            int col = col0 + (wc * 4 + j) * 16 + lm;
#pragma unroll
            for (int r = 0; r < 4; ++r)
                if (okr[r]) Hout[(size_t)(rbase + r) * H1v + col] = f2bf(acc[i][j][r] * dv[r]);
        }
    }
}

// ---------------- GEMM 2: [N,256] @ [256,32] fp32 in, *dinv, bf16 out ----------------

__global__ __launch_bounds__(256) void k_gemm2(const float* __restrict__ A,
                                               const float* __restrict__ W,
                                               const float* __restrict__ dinv,
                                               unsigned short* __restrict__ Hout) {
    __shared__ float Ws[H1v * H2v];  // 32 KB
    const int tid = threadIdx.x;
#pragma unroll
    for (int i = 0; i < 8; ++i) {
        int off = tid * 4 + i * 1024;
        *(float4*)(&Ws[off]) = *(const float4*)(W + off);
    }
    __syncthreads();

    const int row = blockIdx.x * 8 + (tid >> 5);
    const int col = tid & 31;
    if (row >= N) return;
    const float* arow = A + (size_t)row * H1v;
    float sum = 0.f;
#pragma unroll 4
    for (int k = 0; k < H1v; k += 4) {
        float4 a4 = *(const float4*)(arow + k);
        sum = fmaf(a4.x, Ws[(k + 0) * H2v + col], sum);
        sum = fmaf(a4.y, Ws[(k + 1) * H2v + col], sum);
        sum = fmaf(a4.z, Ws[(k + 2) * H2v + col], sum);
        sum = fmaf(a4.w, Ws[(k + 3) * H2v + col], sum);
    }
    Hout[(size_t)row * H2v + col] = f2bf(sum * dinv[row]);
}

// ---------------- CSR aggregation (atomic-free, bf16 messages, fp32 accum) -------
// h holds bf16 h'[i] = dinv[i]*(a@W)[i].  out[d] = dinv[d]*(sum h'[s] + h'[d]) + b

__global__ __launch_bounds__(256) void k_agg_d256(const unsigned short* __restrict__ h,
                                                  const int* __restrict__ rp,
                                                  const int* __restrict__ srcs,
                                                  const float* __restrict__ dinv,
                                                  const float* __restrict__ bias,
                                                  float* __restrict__ out) {
    const int wave = threadIdx.x >> 6;
    const int lane = threadIdx.x & 63;
    const int d = blockIdx.x * 4 + wave;
    if (d >= N) return;
    const int beg = rp[d], end = rp[d + 1];
    const int fo = lane * 4;
    us4 sv = *(const us4*)(h + (size_t)d * H1v + fo);  // self-loop
    float ax = bf2f(sv.x), ay = bf2f(sv.y), az = bf2f(sv.z), aw = bf2f(sv.w);
    int j = beg;
    for (; j + 3 < end; j += 4) {  // 4 independent gathers in flight
        int s0 = srcs[j], s1 = srcs[j + 1], s2 = srcs[j + 2], s3 = srcs[j + 3];
        us4 v0 = *(const us4*)(h + (size_t)s0 * H1v + fo);
        us4 v1 = *(const us4*)(h + (size_t)s1 * H1v + fo);
        us4 v2 = *(const us4*)(h + (size_t)s2 * H1v + fo);
        us4 v3 = *(const us4*)(h + (size_t)s3 * H1v + fo);
        ax += bf2f(v0.x) + bf2f(v1.x) + bf2f(v2.x) + bf2f(v3.x);
        ay += bf2f(v0.y) + bf2f(v1.y) + bf2f(v2.y) + bf2f(v3.y);
        az += bf2f(v0.z) + bf2f(v1.z) + bf2f(v2.z) + bf2f(v3.z);
        aw += bf2f(v0.w) + bf2f(v1.w) + bf2f(v2.w) + bf2f(v3.w);
    }
    for (; j < end; ++j) {
        us4 v = *(const us4*)(h + (size_t)srcs[j] * H1v + fo);
        ax += bf2f(v.x); ay += bf2f(v.y); az += bf2f(v.z); aw += bf2f(v.w);
    }
    const float di = dinv[d];
    const float4 b4 = *(const float4*)(bias + fo);
    float4 o;
    o.x = fmaxf(fmaf(di, ax, b4.x), 0.f);
    o.y = fmaxf(fmaf(di, ay, b4.y), 0.f);
    o.z = fmaxf(fmaf(di, az, b4.z), 0.f);
    o.w = fmaxf(fmaf(di, aw, b4.w), 0.f);
    *(float4*)(out + (size_t)d * H1v + fo) = o;
}

// ---------------- fused: agg over h2 (D=32) + GEMM3 [32x16] -> h3 bf16 ----------
// Block = 8 dst rows. Phase 1: thread (sub,f) aggregates row sub, dim f; a2 row
// (relu(dinv*sum+b2)) goes to LDS (padded stride 33). Phase 2: threads 0..127
// compute 8x16 GEMM3 outputs from LDS, *dinv, store bf16. Kills the a2 buffer.

__global__ __launch_bounds__(256) void k_agg32_gemm3(const unsigned short* __restrict__ h2,
                                                     const int* __restrict__ rp,
                                                     const int* __restrict__ srcs,
                                                     const float* __restrict__ dinv,
                                                     const float* __restrict__ b2,
                                                     const float* __restrict__ W3,
                                                     unsigned short* __restrict__ h3) {
    __shared__ float als[8][33];       // +1 pad: kills 4-way stride-32 conflicts
    __shared__ float W3s[H2v * Cv];    // 512 floats
    const int t = threadIdx.x;
    *(float2*)(&W3s[t * 2]) = *(const float2*)(W3 + t * 2);

    const int sub = t >> 5, f = t & 31;
    const int d = blockIdx.x * 8 + sub;  // N % 8 == 0
    const int beg = rp[d], end = rp[d + 1];
    float acc = bf2f(h2[(size_t)d * H2v + f]);  // self-loop
    int j = beg;
    for (; j + 3 < end; j += 4) {
        float v0 = bf2f(h2[(size_t)srcs[j] * H2v + f]);
        float v1 = bf2f(h2[(size_t)srcs[j + 1] * H2v + f]);
        float v2 = bf2f(h2[(size_t)srcs[j + 2] * H2v + f]);
        float v3 = bf2f(h2[(size_t)srcs[j + 3] * H2v + f]);
        acc += v0 + v1 + v2 + v3;
    }
    for (; j < end; ++j) acc += bf2f(h2[(size_t)srcs[j] * H2v + f]);
    als[sub][f] = fmaxf(fmaf(dinv[d], acc, b2[f]), 0.f);
    __syncthreads();

    if (t < 128) {
        const int row = t >> 4, col = t & 15;
        float sum = 0.f;
#pragma unroll
        for (int k = 0; k < H2v; ++k) sum = fmaf(als[row][k], W3s[k * Cv + col], sum);
        const int gr = blockIdx.x * 8 + row;
        h3[(size_t)gr * Cv + col] = f2bf(sum * dinv[gr]);
    }
}

// ---------------- final aggregation over h3 (D=16) -> out fp32 ----------------

__global__ __launch_bounds__(256) void k_agg16(const unsigned short* __restrict__ h,
                                               const int* __restrict__ rp,
                                               const int* __restrict__ srcs,
                                               const float* __restrict__ dinv,
                                               const float* __restrict__ bias,
                                               float* __restrict__ out) {
    const int sub = threadIdx.x >> 4;
    const int f = threadIdx.x & 15;
    const int d = blockIdx.x * 16 + sub;
    if (d >= N) return;
    const int beg = rp[d], end = rp[d + 1];
    float acc = bf2f(h[(size_t)d * Cv + f]);  // self-loop
    int j = beg;
    for (; j + 3 < end; j += 4) {
        float v0 = bf2f(h[(size_t)srcs[j] * Cv + f]);
        float v1 = bf2f(h[(size_t)srcs[j + 1] * Cv + f]);
        float v2 = bf2f(h[(size_t)srcs[j + 2] * Cv + f]);
        float v3 = bf2f(h[(size_t)srcs[j + 3] * Cv + f]);
        acc += v0 + v1 + v2 + v3;
    }
    for (; j < end; ++j) acc += bf2f(h[(size_t)srcs[j] * Cv + f]);
    out[(size_t)d * Cv + f] = fmaf(dinv[d], acc, bias[f]);
}

// ---------------- launch ----------------

extern "C" void kernel_launch(void* const* d_in, const int* in_sizes, int n_in,
                              void* d_out, int out_size, void* d_ws, size_t ws_size,
                              hipStream_t stream) {
    const float* x  = (const float*)d_in[0];
    const int*   ei = (const int*)d_in[1];
    const float* W1 = (const float*)d_in[2];
    const float* b1 = (const float*)d_in[3];
    const float* W2 = (const float*)d_in[4];
    const float* b2 = (const float*)d_in[5];
    const float* W3 = (const float*)d_in[6];
    const float* b3 = (const float*)d_in[7];
    const int* src = ei;       // edge_index[0]
    const int* dst = ei + E;   // edge_index[1]
    float* out = (float*)d_out;

    // Workspace layout (bytes):
    // [0       ] dinv    float[50000]
    // [0x40000 ] cnt/rp  int[50001]   (in-place scan)
    // [0x80000 ] cursor  int[50000]
    // [0xB2000 ] bsum    int[49]
    // [0xC0000 ] srcs    int[800000]
    // [4 MiB   ] Wsplit  ushort[262144]  (512 KB)
    // [5 MiB   ] h1 bf16, a1 fp32, h2 bf16, h3 bf16   (a2 eliminated)
    char* ws = (char*)d_ws;
    float* dinv   = (float*)ws;
    int*   cnt    = (int*)(ws + 0x40000);
    int*   rp     = cnt;
    int*   cursor = (int*)(ws + 0x80000);
    int*   bsum   = (int*)(ws + 0xB2000);
    int*   srcs   = (int*)(ws + 0xC0000);
    unsigned short* wsplit = (unsigned short*)(ws + (size_t)4 * 1024 * 1024);
    char* p = ws + (size_t)5 * 1024 * 1024;
    unsigned short* h1 = (unsigned short*)p; p += (size_t)N * H1v * sizeof(unsigned short);
    float*          a1 = (float*)p;          p += (size_t)N * H1v * sizeof(float);
    unsigned short* h2 = (unsigned short*)p; p += (size_t)N * H2v * sizeof(unsigned short);
    unsigned short* h3 = (unsigned short*)p;

    // CSR build + weight split: 5 dispatches
    k_init<<<64 + (N + 256) / 256, 256, 0, stream>>>(W1, wsplit, cnt);
    k_hist<<<(E + 255) / 256, 256, 0, stream>>>(dst, cnt);
    k_scan_part<<<NBLK, 256, 0, stream>>>(cnt, bsum);
    k_scan_final<<<NBLK, 256, 0, stream>>>(cnt, bsum, rp, cursor, dinv);
    k_permute<<<(E + 255) / 256, 256, 0, stream>>>(src, dst, cursor, srcs);

    // ---- layer 1: 512 -> 256 (MFMA, LDS-free), ReLU ----
    dim3 g1((N + 127) / 128, 2);
    k_gemm1_mfma<<<g1, 256, 0, stream>>>(x, wsplit, dinv, h1);
    k_agg_d256<<<(N + 3) / 4, 256, 0, stream>>>(h1, rp, srcs, dinv, b1, a1);

    // ---- layer 2: 256 -> 32, ReLU ----
    k_gemm2<<<N / 8, 256, 0, stream>>>(a1, W2, dinv, h2);

    // ---- fused: agg(h2) + GEMM3 -> h3 ----
    k_agg32_gemm3<<<N / 8, 256, 0, stream>>>(h2, rp, srcs, dinv, b2, W3, h3);

    // ---- final aggregation -> out ----
    k_agg16<<<(N + 15) / 16, 256, 0, stream>>>(h3, rp, srcs, dinv, b3, out);
}